// Round 1
// baseline (844.621 us; speedup 1.0000x reference)
//
#include <hip/hip_runtime.h>

// Segmented polynomial: out[n, u*4+s] = sum_{e: dst[e]==n} x[src[e], u] * sh[e, s]
// N=100000, U=32, S=4, E=3200000.
// Strategy: counting-sort edges by dst into d_ws, then one block per node
// accumulates its edges in registers (no float atomics), one coalesced store.

#define U_DIM 32
#define S_DIM 4
#define US 128

constexpr int SCAN_BLOCK = 256;
constexpr int SCAN_ITEMS = 8;
constexpr int SCAN_CHUNK = SCAN_BLOCK * SCAN_ITEMS; // 2048

__global__ void hist_kernel(const int* __restrict__ dst, int* __restrict__ counts, int E) {
    int i = blockIdx.x * blockDim.x + threadIdx.x;
    if (i < E) atomicAdd(&counts[dst[i]], 1);
}

__global__ void block_sum_kernel(const int* __restrict__ counts, int* __restrict__ bsums, int N) {
    __shared__ int sdata[SCAN_BLOCK];
    int base = blockIdx.x * SCAN_CHUNK;
    int sum = 0;
    for (int j = 0; j < SCAN_ITEMS; ++j) {
        int idx = base + j * SCAN_BLOCK + threadIdx.x;
        if (idx < N) sum += counts[idx];
    }
    sdata[threadIdx.x] = sum;
    __syncthreads();
    for (int off = SCAN_BLOCK / 2; off > 0; off >>= 1) {
        if (threadIdx.x < off) sdata[threadIdx.x] += sdata[threadIdx.x + off];
        __syncthreads();
    }
    if (threadIdx.x == 0) bsums[blockIdx.x] = sdata[0];
}

__global__ void scan_bsums_kernel(int* __restrict__ bsums, int nb) {
    if (threadIdx.x == 0 && blockIdx.x == 0) {
        int acc = 0;
        for (int i = 0; i < nb; ++i) { int v = bsums[i]; bsums[i] = acc; acc += v; }
    }
}

__global__ void scan_final_kernel(const int* __restrict__ counts, const int* __restrict__ bsums,
                                  int* __restrict__ offsets, int N, int E) {
    __shared__ int sdata[SCAN_BLOCK];
    int base = blockIdx.x * SCAN_CHUNK + threadIdx.x * SCAN_ITEMS;
    int local[SCAN_ITEMS];
    int tsum = 0;
    for (int j = 0; j < SCAN_ITEMS; ++j) {
        int idx = base + j;
        int v = (idx < N) ? counts[idx] : 0;
        local[j] = tsum;      // exclusive within thread
        tsum += v;
    }
    sdata[threadIdx.x] = tsum;
    __syncthreads();
    // Hillis-Steele inclusive scan of per-thread sums
    for (int off = 1; off < SCAN_BLOCK; off <<= 1) {
        int v = (threadIdx.x >= off) ? sdata[threadIdx.x - off] : 0;
        __syncthreads();
        sdata[threadIdx.x] += v;
        __syncthreads();
    }
    int excl = sdata[threadIdx.x] - tsum + bsums[blockIdx.x];
    for (int j = 0; j < SCAN_ITEMS; ++j) {
        int idx = base + j;
        if (idx < N) offsets[idx] = excl + local[j];
    }
    if (blockIdx.x == 0 && threadIdx.x == 0) offsets[N] = E;
}

__global__ void scatter_kernel(const int* __restrict__ dst, const int* __restrict__ offsets,
                               int* __restrict__ cursors, int* __restrict__ edge_list, int E) {
    int e = blockIdx.x * blockDim.x + threadIdx.x;
    if (e < E) {
        int d = dst[e];
        int pos = offsets[d] + atomicAdd(&cursors[d], 1);
        edge_list[pos] = e;
    }
}

// One block per node; 128 threads, thread t owns output element (u = t>>2, s = t&3).
__global__ void __launch_bounds__(US) accum_kernel(
        const float* __restrict__ x, const float* __restrict__ sh,
        const int* __restrict__ src, const int* __restrict__ offsets,
        const int* __restrict__ edge_list, float* __restrict__ out) {
    int n = blockIdx.x;
    int t = threadIdx.x;
    int u = t >> 2;
    int s = t & 3;
    int beg = offsets[n];
    int end = offsets[n + 1];
    float acc = 0.f;
    for (int i = beg; i < end; ++i) {
        int e = edge_list[i];         // uniform within block -> broadcast load
        int sv = src[e];              // uniform within block -> broadcast load
        acc += x[sv * U_DIM + u] * sh[e * S_DIM + s];
    }
    out[(size_t)n * US + t] = acc;
}

// Fallback if workspace is too small: pure atomic scatter-add.
__global__ void __launch_bounds__(US) atomic_kernel(
        const float* __restrict__ x, const float* __restrict__ sh,
        const int* __restrict__ src, const int* __restrict__ dst,
        float* __restrict__ out, int E) {
    int e = blockIdx.x;
    int t = threadIdx.x;
    float v = x[src[e] * U_DIM + (t >> 2)] * sh[e * S_DIM + (t & 3)];
    atomicAdd(&out[(size_t)dst[e] * US + t], v);
}

extern "C" void kernel_launch(void* const* d_in, const int* in_sizes, int n_in,
                              void* d_out, int out_size, void* d_ws, size_t ws_size,
                              hipStream_t stream) {
    const float* x  = (const float*)d_in[0];
    const float* sh = (const float*)d_in[1];
    const int* src  = (const int*)d_in[2];
    const int* dst  = (const int*)d_in[3];
    float* out = (float*)d_out;

    const int E = in_sizes[2];
    const int N = in_sizes[0] / U_DIM;
    const int nb = (N + SCAN_CHUNK - 1) / SCAN_CHUNK;

    // Workspace layout: counts[N] | offsets[N+1] | bsums[nb] | edge_list[E]
    size_t need = sizeof(int) * ((size_t)N + (size_t)(N + 1) + (size_t)nb + (size_t)E);

    if (ws_size >= need) {
        int* counts    = (int*)d_ws;
        int* offsets   = counts + N;
        int* bsums     = offsets + N + 1;
        int* edge_list = bsums + nb;

        hipMemsetAsync(counts, 0, sizeof(int) * (size_t)N, stream);
        hist_kernel<<<(E + 255) / 256, 256, 0, stream>>>(dst, counts, E);
        block_sum_kernel<<<nb, SCAN_BLOCK, 0, stream>>>(counts, bsums, N);
        scan_bsums_kernel<<<1, 64, 0, stream>>>(bsums, nb);
        scan_final_kernel<<<nb, SCAN_BLOCK, 0, stream>>>(counts, bsums, offsets, N, E);
        hipMemsetAsync(counts, 0, sizeof(int) * (size_t)N, stream);  // reuse as cursors
        scatter_kernel<<<(E + 255) / 256, 256, 0, stream>>>(dst, offsets, counts, edge_list, E);
        accum_kernel<<<N, US, 0, stream>>>(x, sh, src, offsets, edge_list, out);
    } else {
        hipMemsetAsync(out, 0, sizeof(float) * (size_t)out_size, stream);
        atomic_kernel<<<E, US, 0, stream>>>(x, sh, src, dst, out, E);
    }
}